// Round 2
// baseline (3869.456 us; speedup 1.0000x reference)
//
#include <hip/hip_runtime.h>
#include <hip/hip_bf16.h>

// Problem dims (AttentivePoolingNetwork)
#define BB   128
#define LQ   128
#define LA   512
#define EMBD 300
#define FILT 400
#define KW   3
#define RED  900   // EMBD*KW

typedef unsigned short u16;
typedef unsigned int   u32;

__device__ __forceinline__ float b2f(u16 h){ return __uint_as_float(((u32)h) << 16); }
__device__ __forceinline__ u16 f2b(float f){
  u32 u = __float_as_uint(f);
  u32 r = (u + 0x7FFFu + ((u >> 16) & 1u)) >> 16;   // round-to-nearest-even
  return (u16)r;
}
// order-preserving float -> uint encoding (for atomicMax on floats)
__device__ __forceinline__ u32 encf(float f){
  u32 u = __float_as_uint(f);
  return (u & 0x80000000u) ? ~u : (u | 0x80000000u);
}
__device__ __forceinline__ float decf(u32 k){
  u32 u = (k & 0x80000000u) ? (k ^ 0x80000000u) : ~k;
  return __uint_as_float(u);
}

// conv_w [F][E][K] fp32 -> wT [E*K][F] fp32  (r = e*3+k major, f contiguous)
__global__ void k_wt(const float* __restrict__ w, float* __restrict__ wT){
  int idx = blockIdx.x * 256 + threadIdx.x;
  if (idx < RED * FILT){
    int r = idx / FILT, f = idx - r * FILT;
    wT[idx] = w[f * RED + r];
  }
}

// Embed + conv1d(pad=1): out[b][l][f] = bias[f] + sum_{e,k} emb[tok[b][l+k-1]][e] * w[f][e][k]
// grid (L/16, B), 256 threads = 16 l-rows x 16 f-groups, 25 f per thread. out is bf16.
__global__ __launch_bounds__(256) void k_encode(const int* __restrict__ toks,
    const float* __restrict__ emb, const float* __restrict__ wT, const float* __restrict__ bias,
    u16* __restrict__ out, int L){
  __shared__ float xs[18][304];
  int b = blockIdx.y, l0 = blockIdx.x * 16;
  int tid = threadIdx.x;
  for (int i = tid; i < 18 * EMBD; i += 256){
    int row = i / EMBD, e = i - row * EMBD;
    int pos = l0 - 1 + row;
    float v = 0.f;
    if (pos >= 0 && pos < L){
      int t = toks[b * L + pos];
      v = emb[t * EMBD + e];     // emb row 0 is all-zero (padding_idx)
    }
    xs[row][e] = v;
  }
  __syncthreads();
  int ty = tid >> 4, tx = tid & 15;
  float acc[25];
  #pragma unroll
  for (int j = 0; j < 25; j++) acc[j] = 0.f;
  for (int e = 0; e < EMBD; e++){
    float x0 = xs[ty    ][e];   // k=0 -> pos l-1
    float x1 = xs[ty + 1][e];   // k=1 -> pos l
    float x2 = xs[ty + 2][e];   // k=2 -> pos l+1
    const float* wrow = wT + (e * 3) * FILT + tx;
    #pragma unroll
    for (int j = 0; j < 25; j++) acc[j] += x0 * wrow[16 * j];
    #pragma unroll
    for (int j = 0; j < 25; j++) acc[j] += x1 * wrow[FILT + 16 * j];
    #pragma unroll
    for (int j = 0; j < 25; j++) acc[j] += x2 * wrow[2 * FILT + 16 * j];
  }
  size_t obase = ((size_t)(b * L + l0 + ty)) * FILT + tx;
  #pragma unroll
  for (int j = 0; j < 25; j++)
    out[obase + 16 * j] = f2b(acc[j] + bias[tx + 16 * j]);
}

// T[b][q][g] = sum_f QT[b][q][f] * W[f][g].  QT bf16, W fp32, T bf16.
// grid (LQ/16, B), 256 threads = 16 q-rows x 16 g-groups, 25 g per thread.
__global__ __launch_bounds__(256) void k_gemmT(const u16* __restrict__ QT,
    const float* __restrict__ W, u16* __restrict__ T){
  __shared__ u16 qs[16][408];
  int b = blockIdx.y, q0 = blockIdx.x * 16;
  int tid = threadIdx.x;
  for (int i = tid; i < 16 * FILT; i += 256){
    int r = i / FILT, c = i - r * FILT;
    qs[r][c] = QT[((size_t)(b * LQ + q0 + r)) * FILT + c];
  }
  __syncthreads();
  int ty = tid >> 4, tx = tid & 15;
  float acc[25];
  #pragma unroll
  for (int j = 0; j < 25; j++) acc[j] = 0.f;
  for (int k = 0; k < FILT; k++){
    float qv = b2f(qs[ty][k]);
    const float* wrow = W + k * FILT + tx;
    #pragma unroll
    for (int j = 0; j < 25; j++) acc[j] += qv * wrow[16 * j];
  }
  size_t obase = ((size_t)(b * LQ + q0 + ty)) * FILT + tx;
  #pragma unroll
  for (int j = 0; j < 25; j++) T[obase + 16 * j] = f2b(acc[j]);
}

// Raw scores S[b][q][a] = sum_g T[b][q][g] * AT[b][a][g]; row/col maxes only.
// tanh is monotonic -> applied later to the maxes. grid (LA/128, B).
// Block: full 128 q x 128-a tile; thread: 8x8 register tile. T/AT bf16.
__global__ __launch_bounds__(256) void k_scores(const u16* __restrict__ T,
    const u16* __restrict__ AT, u32* __restrict__ rowmaxE, float* __restrict__ colmax){
  __shared__ u32 Tu[128][9];       // [q][pair-of-g]
  __shared__ u32 Au[128][9];       // [a][pair-of-g]
  __shared__ float rpart[128][17]; // [q][a-group]
  __shared__ float cpart[128][17]; // [a][q-group]
  int b = blockIdx.y, a0 = blockIdx.x * 128;
  int tid = threadIdx.x;
  int qg = tid & 15, ag = tid >> 4;
  int qb = qg * 8, ab = ag * 8;
  float acc[8][8];
  #pragma unroll
  for (int i = 0; i < 8; i++)
    #pragma unroll
    for (int j = 0; j < 8; j++) acc[i][j] = 0.f;

  for (int g0 = 0; g0 < FILT; g0 += 16){
    __syncthreads();
    for (int i = tid; i < 128 * 8; i += 256){
      int r = i >> 3, k2 = i & 7;
      Tu[r][k2] = *reinterpret_cast<const u32*>(T  + ((size_t)(b * LQ + r))      * FILT + g0 + 2 * k2);
      Au[r][k2] = *reinterpret_cast<const u32*>(AT + ((size_t)(b * LA + a0 + r)) * FILT + g0 + 2 * k2);
    }
    __syncthreads();
    #pragma unroll
    for (int kk = 0; kk < 8; kk++){
      float tl[8], th[8], al[8], ah[8];
      #pragma unroll
      for (int i = 0; i < 8; i++){
        u32 u = Tu[qb + i][kk];
        tl[i] = __uint_as_float(u << 16);
        th[i] = __uint_as_float(u & 0xFFFF0000u);
      }
      #pragma unroll
      for (int j = 0; j < 8; j++){
        u32 u = Au[ab + j][kk];
        al[j] = __uint_as_float(u << 16);
        ah[j] = __uint_as_float(u & 0xFFFF0000u);
      }
      #pragma unroll
      for (int i = 0; i < 8; i++)
        #pragma unroll
        for (int j = 0; j < 8; j++)
          acc[i][j] += tl[i] * al[j] + th[i] * ah[j];
    }
  }
  #pragma unroll
  for (int i = 0; i < 8; i++){
    float m = acc[i][0];
    #pragma unroll
    for (int j = 1; j < 8; j++) m = fmaxf(m, acc[i][j]);
    rpart[qb + i][ag] = m;
  }
  #pragma unroll
  for (int j = 0; j < 8; j++){
    float m = acc[0][j];
    #pragma unroll
    for (int i = 1; i < 8; i++) m = fmaxf(m, acc[i][j]);
    cpart[ab + j][qg] = m;
  }
  __syncthreads();
  if (tid < 128){
    float m = rpart[tid][0];
    #pragma unroll
    for (int g = 1; g < 16; g++) m = fmaxf(m, rpart[tid][g]);
    atomicMax(&rowmaxE[b * LQ + tid], encf(m));     // combine across a-tiles
    float m2 = cpart[tid][0];
    #pragma unroll
    for (int g = 1; g < 16; g++) m2 = fmaxf(m2, cpart[tid][g]);
    colmax[b * LA + a0 + tid] = m2;                 // full q range in-block
  }
}

// Per-batch: tanh(maxes) -> softmax -> pooled rQ/rA -> cosine similarity (fp32 out).
__global__ __launch_bounds__(256) void k_final(const u16* __restrict__ QT,
    const u16* __restrict__ AT, const u32* __restrict__ rowmaxE,
    const float* __restrict__ colmax, float* __restrict__ outp){
  __shared__ float roq[128];
  __shared__ float roa[512];
  __shared__ float rqs[FILT];
  __shared__ float ras[FILT];
  __shared__ float sred[2];
  int b = blockIdx.x, tid = threadIdx.x;
  if (tid < 128) roq[tid] = tanhf(decf(rowmaxE[b * LQ + tid]));
  for (int i = tid; i < 512; i += 256) roa[i] = tanhf(colmax[b * LA + i]);
  __syncthreads();
  if (tid == 0){ float m = roq[0]; for (int q = 1; q < 128; q++) m = fmaxf(m, roq[q]); sred[0] = m; }
  if (tid == 1){ float m = roa[0]; for (int a = 1; a < 512; a++) m = fmaxf(m, roa[a]); sred[1] = m; }
  __syncthreads();
  if (tid < 128) roq[tid] = __expf(roq[tid] - sred[0]);
  for (int i = tid; i < 512; i += 256) roa[i] = __expf(roa[i] - sred[1]);
  __syncthreads();
  if (tid == 0){ float s = 0; for (int q = 0; q < 128; q++) s += roq[q]; sred[0] = s; }
  if (tid == 1){ float s = 0; for (int a = 0; a < 512; a++) s += roa[a]; sred[1] = s; }
  __syncthreads();
  if (tid < 128) roq[tid] /= sred[0];
  for (int i = tid; i < 512; i += 256) roa[i] /= sred[1];
  __syncthreads();
  for (int f = tid; f < FILT; f += 256){
    float rq = 0.f, ra = 0.f;
    for (int q = 0; q < LQ; q++) rq += b2f(QT[((size_t)(b * LQ + q)) * FILT + f]) * roq[q];
    for (int a = 0; a < LA; a++) ra += b2f(AT[((size_t)(b * LA + a)) * FILT + f]) * roa[a];
    rqs[f] = rq; ras[f] = ra;
  }
  __syncthreads();
  if (tid == 0){
    float dot = 0, n1 = 0, n2 = 0;
    for (int f = 0; f < FILT; f++){ dot += rqs[f] * ras[f]; n1 += rqs[f] * rqs[f]; n2 += ras[f] * ras[f]; }
    float nq = fmaxf(sqrtf(n1), 1e-8f);
    float na = fmaxf(sqrtf(n2), 1e-8f);
    outp[b] = dot / (nq * na);
  }
}

extern "C" void kernel_launch(void* const* d_in, const int* in_sizes, int n_in,
                              void* d_out, int out_size, void* d_ws, size_t ws_size,
                              hipStream_t stream){
  const int*   qtok = (const int*)d_in[0];
  const int*   atok = (const int*)d_in[1];
  const float* emb  = (const float*)d_in[2];
  const float* cw   = (const float*)d_in[3];
  const float* cb   = (const float*)d_in[4];
  const float* W    = (const float*)d_in[5];
  float* outp = (float*)d_out;

  char* ws = (char*)d_ws;
  size_t off = 0;
  auto alloc = [&](size_t bytes) -> char* {
    char* p = ws + off;
    off = (off + bytes + 255) & ~(size_t)255;
    return p;
  };
  float* wT = (float*)alloc((size_t)RED * FILT * 4);    // 1.44 MB
  u16*   QT = (u16*)alloc((size_t)BB * LQ * FILT * 2);  // 13.1 MB
  u16*   AT = (u16*)alloc((size_t)BB * LA * FILT * 2);  // 52.4 MB
  u16*   T  = (u16*)alloc((size_t)BB * LQ * FILT * 2);  // 13.1 MB
  u32*   rme = (u32*)alloc((size_t)BB * LQ * 4);
  float* cm  = (float*)alloc((size_t)BB * LA * 4);

  hipMemsetAsync(rme, 0, (size_t)BB * LQ * 4, stream);  // encodes as -inf sentinel

  k_wt<<<dim3((RED * FILT + 255) / 256), 256, 0, stream>>>(cw, wT);
  k_encode<<<dim3(LQ / 16, BB), 256, 0, stream>>>(qtok, emb, wT, cb, QT, LQ);
  k_encode<<<dim3(LA / 16, BB), 256, 0, stream>>>(atok, emb, wT, cb, AT, LA);
  k_gemmT<<<dim3(LQ / 16, BB), 256, 0, stream>>>(QT, W, T);
  k_scores<<<dim3(LA / 128, BB), 256, 0, stream>>>(T, AT, rme, cm);
  k_final<<<BB, 256, 0, stream>>>(QT, AT, rme, cm, outp);
}

// Round 3
// 1159.709 us; speedup vs baseline: 3.3366x; 3.3366x over previous
//
#include <hip/hip_runtime.h>
#include <hip/hip_bf16.h>

// Problem dims (AttentivePoolingNetwork)
#define BB   128
#define LQ   128
#define LA   512
#define EMBD 300
#define FILT 400
#define KW   3

#define NT   25    // n-tiles of 16 (400)
#define KC   30    // k-chunks of 32 (3 emb-blocks padded to 320 each)
#define MT   64    // rows per block

typedef unsigned short u16;
typedef unsigned int   u32;
typedef __attribute__((ext_vector_type(4))) int    i32x4;
typedef __attribute__((ext_vector_type(4))) float  f32x4;
typedef __attribute__((ext_vector_type(8))) __bf16 bf16x8;

__device__ __forceinline__ float b2f(u16 h){ return __uint_as_float(((u32)h) << 16); }
__device__ __forceinline__ u16 f2b(float f){
  u32 u = __float_as_uint(f);
  u32 r = (u + 0x7FFFu + ((u >> 16) & 1u)) >> 16;   // RNE
  return (u16)r;
}
// order-preserving float -> uint encoding (for atomicMax on floats)
__device__ __forceinline__ u32 encf(float f){
  u32 u = __float_as_uint(f);
  return (u & 0x80000000u) ? ~u : (u | 0x80000000u);
}
__device__ __forceinline__ float decf(u32 k){
  u32 u = (k & 0x80000000u) ? (k ^ 0x80000000u) : ~k;
  return __uint_as_float(u);
}

// conv_w [F][E][K] fp32 -> wTf in MFMA B-fragment order:
// wTf[kc][nt][lane][j] (bf16), element = B[k'=kc*32+quad*8+j][n=nt*16+(lane&15)]
// where k' -> (kk = k'/320, e = k'%320), value = (e<300) ? conv_w[n][e][kk] : 0.
__global__ void k_wt2(const float* __restrict__ cw, u32* __restrict__ wTf){
  int idx = blockIdx.x * 256 + threadIdx.x;     // one thread per (kc,nt,lane)
  if (idx >= KC * NT * 64) return;
  int kc  = idx / (NT * 64);
  int rem = idx - kc * (NT * 64);
  int nt  = rem >> 6;
  int lane = rem & 63;
  int n = nt * 16 + (lane & 15);
  int quad = lane >> 4;
  u32 pack[4];
  #pragma unroll
  for (int d = 0; d < 4; d++){
    u16 h[2];
    #pragma unroll
    for (int s = 0; s < 2; s++){
      int kp = kc * 32 + quad * 8 + 2 * d + s;
      int kk = kp / 320, e = kp - kk * 320;
      float v = (e < EMBD) ? cw[(size_t)n * (EMBD * KW) + e * KW + kk] : 0.f;
      h[s] = f2b(v);
    }
    pack[d] = (u32)h[0] | ((u32)h[1] << 16);
  }
  i32x4 out4; out4.x = pack[0]; out4.y = pack[1]; out4.z = pack[2]; out4.w = pack[3];
  *((i32x4*)wTf + idx) = out4;
}

// Embed + conv1d(pad=1) as MFMA GEMM.
// X[row][k'=kk*320+e] = emb[tok[pos=row_global+kk-1]][e]; OUT[row][n] = X·Wt + bias.
// grid = (B*L)/64 blocks, 256 threads (4 waves). Each block: 64 rows x 400 cols.
__global__ __launch_bounds__(256) void k_encode_mfma(const int* __restrict__ toks,
    const float* __restrict__ emb, const u32* __restrict__ wTf,
    const float* __restrict__ bias, u16* __restrict__ out, int L){
  __shared__ u16 At[66 * 328];   // emb tile, bf16, stride 328 (2-way bank alias only)
  __shared__ u16 Bb[13 * 512];   // B-fragment half-chunk: 13 tiles x 1024B

  const int tid  = threadIdx.x;
  const int w    = tid >> 6;
  const int lane = tid & 63;
  const int col  = lane & 15;
  const int quad = lane >> 4;
  const int row0 = blockIdx.x * MT;
  const int b    = row0 / L;
  const int l0   = row0 - b * L;

  // zero A-tile (incl. e-pad cols 300..319 and OOB rows)
  for (int i = tid; i < 66 * 328 / 2; i += 256) ((u32*)At)[i] = 0u;
  __syncthreads();
  // fill: 66 rows x 75 float4-groups, fp32 emb -> bf16 LDS
  for (int i = tid; i < 66 * 75; i += 256){
    int r = i / 75, c4 = i - r * 75;
    int pos = l0 - 1 + r;
    if ((unsigned)pos < (unsigned)L){
      int t = toks[b * L + pos];
      float4 v = *((const float4*)(emb + (size_t)t * EMBD) + c4);
      u32 p0 = (u32)f2b(v.x) | ((u32)f2b(v.y) << 16);
      u32 p1 = (u32)f2b(v.z) | ((u32)f2b(v.w) << 16);
      int di = (r * 328 + c4 * 4) >> 1;
      ((u32*)At)[di]     = p0;
      ((u32*)At)[di + 1] = p1;
    }
  }

  f32x4 acc[7][4];
  #pragma unroll
  for (int j = 0; j < 7; j++)
    #pragma unroll
    for (int mf = 0; mf < 4; mf++)
      acc[j][mf] = (f32x4){0.f, 0.f, 0.f, 0.f};

  __syncthreads();

  for (int kc = 0; kc < KC; kc++){
    int kk = kc / 10;
    int e0 = (kc - kk * 10) * 32;
    // A-fragments for this k-chunk (4 m-frags, reused across both halves)
    bf16x8 afr[4];
    {
      int ebase = e0 + quad * 8;
      #pragma unroll
      for (int mf = 0; mf < 4; mf++){
        int r = mf * 16 + col + kk;
        afr[mf] = __builtin_bit_cast(bf16x8, *(const i32x4*)(At + r * 328 + ebase));
      }
    }
    // ---- half 0: nt 0..12 ----
    __syncthreads();
    {
      const i32x4* src = (const i32x4*)wTf + (size_t)(kc * NT) * 64;
      i32x4* dst = (i32x4*)Bb;
      for (int i = tid; i < 13 * 64; i += 256) dst[i] = src[i];
    }
    __syncthreads();
    #pragma unroll
    for (int j = 0; j < 4; j++){
      int nt = w + 4 * j;
      if (nt <= 12){
        bf16x8 bfr = __builtin_bit_cast(bf16x8, *((const i32x4*)Bb + nt * 64 + lane));
        #pragma unroll
        for (int mf = 0; mf < 4; mf++)
          acc[j][mf] = __builtin_amdgcn_mfma_f32_16x16x32_bf16(afr[mf], bfr, acc[j][mf], 0, 0, 0);
      }
    }
    // ---- half 1: nt 13..24 ----
    __syncthreads();
    {
      const i32x4* src = (const i32x4*)wTf + ((size_t)(kc * NT) + 13) * 64;
      i32x4* dst = (i32x4*)Bb;
      for (int i = tid; i < 12 * 64; i += 256) dst[i] = src[i];
    }
    __syncthreads();
    #pragma unroll
    for (int j = 0; j < 3; j++){
      int nt = 13 + w + 4 * j;
      bf16x8 bfr = __builtin_bit_cast(bf16x8, *((const i32x4*)Bb + (nt - 13) * 64 + lane));
      #pragma unroll
      for (int mf = 0; mf < 4; mf++)
        acc[4 + j][mf] = __builtin_amdgcn_mfma_f32_16x16x32_bf16(afr[mf], bfr, acc[4 + j][mf], 0, 0, 0);
    }
  }

  // epilogue: + bias, bf16 store. C/D: col=lane&15, row=quad*4+reg.
  #pragma unroll
  for (int j = 0; j < 7; j++){
    int nt = (j < 4) ? (w + 4 * j) : (13 + w + 4 * (j - 4));
    if (j < 4 && nt > 12) continue;
    int n = nt * 16 + col;
    float bv = bias[n];
    #pragma unroll
    for (int mf = 0; mf < 4; mf++){
      int rbase = row0 + mf * 16 + quad * 4;
      #pragma unroll
      for (int r = 0; r < 4; r++)
        out[(size_t)(rbase + r) * FILT + n] = f2b(acc[j][mf][r] + bv);
    }
  }
}

// T[b][q][g] = sum_f QT[b][q][f] * W[f][g].  QT bf16, W fp32, T bf16.
__global__ __launch_bounds__(256) void k_gemmT(const u16* __restrict__ QT,
    const float* __restrict__ W, u16* __restrict__ T){
  __shared__ u16 qs[16][408];
  int b = blockIdx.y, q0 = blockIdx.x * 16;
  int tid = threadIdx.x;
  for (int i = tid; i < 16 * FILT; i += 256){
    int r = i / FILT, c = i - r * FILT;
    qs[r][c] = QT[((size_t)(b * LQ + q0 + r)) * FILT + c];
  }
  __syncthreads();
  int ty = tid >> 4, tx = tid & 15;
  float acc[25];
  #pragma unroll
  for (int j = 0; j < 25; j++) acc[j] = 0.f;
  for (int k = 0; k < FILT; k++){
    float qv = b2f(qs[ty][k]);
    const float* wrow = W + k * FILT + tx;
    #pragma unroll
    for (int j = 0; j < 25; j++) acc[j] += qv * wrow[16 * j];
  }
  size_t obase = ((size_t)(b * LQ + q0 + ty)) * FILT + tx;
  #pragma unroll
  for (int j = 0; j < 25; j++) T[obase + 16 * j] = f2b(acc[j]);
}

// Raw scores S[b][q][a] = sum_g T[b][q][g] * AT[b][a][g]; row/col maxes only.
__global__ __launch_bounds__(256) void k_scores(const u16* __restrict__ T,
    const u16* __restrict__ AT, u32* __restrict__ rowmaxE, float* __restrict__ colmax){
  __shared__ u32 Tu[128][9];
  __shared__ u32 Au[128][9];
  __shared__ float rpart[128][17];
  __shared__ float cpart[128][17];
  int b = blockIdx.y, a0 = blockIdx.x * 128;
  int tid = threadIdx.x;
  int qg = tid & 15, ag = tid >> 4;
  int qb = qg * 8, ab = ag * 8;
  float acc[8][8];
  #pragma unroll
  for (int i = 0; i < 8; i++)
    #pragma unroll
    for (int j = 0; j < 8; j++) acc[i][j] = 0.f;

  for (int g0 = 0; g0 < FILT; g0 += 16){
    __syncthreads();
    for (int i = tid; i < 128 * 8; i += 256){
      int r = i >> 3, k2 = i & 7;
      Tu[r][k2] = *reinterpret_cast<const u32*>(T  + ((size_t)(b * LQ + r))      * FILT + g0 + 2 * k2);
      Au[r][k2] = *reinterpret_cast<const u32*>(AT + ((size_t)(b * LA + a0 + r)) * FILT + g0 + 2 * k2);
    }
    __syncthreads();
    #pragma unroll
    for (int kk = 0; kk < 8; kk++){
      float tl[8], th[8], al[8], ah[8];
      #pragma unroll
      for (int i = 0; i < 8; i++){
        u32 u = Tu[qb + i][kk];
        tl[i] = __uint_as_float(u << 16);
        th[i] = __uint_as_float(u & 0xFFFF0000u);
      }
      #pragma unroll
      for (int j = 0; j < 8; j++){
        u32 u = Au[ab + j][kk];
        al[j] = __uint_as_float(u << 16);
        ah[j] = __uint_as_float(u & 0xFFFF0000u);
      }
      #pragma unroll
      for (int i = 0; i < 8; i++)
        #pragma unroll
        for (int j = 0; j < 8; j++)
          acc[i][j] += tl[i] * al[j] + th[i] * ah[j];
    }
  }
  #pragma unroll
  for (int i = 0; i < 8; i++){
    float m = acc[i][0];
    #pragma unroll
    for (int j = 1; j < 8; j++) m = fmaxf(m, acc[i][j]);
    rpart[qb + i][ag] = m;
  }
  #pragma unroll
  for (int j = 0; j < 8; j++){
    float m = acc[0][j];
    #pragma unroll
    for (int i = 1; i < 8; i++) m = fmaxf(m, acc[i][j]);
    cpart[ab + j][qg] = m;
  }
  __syncthreads();
  if (tid < 128){
    float m = rpart[tid][0];
    #pragma unroll
    for (int g = 1; g < 16; g++) m = fmaxf(m, rpart[tid][g]);
    atomicMax(&rowmaxE[b * LQ + tid], encf(m));
    float m2 = cpart[tid][0];
    #pragma unroll
    for (int g = 1; g < 16; g++) m2 = fmaxf(m2, cpart[tid][g]);
    colmax[b * LA + a0 + tid] = m2;
  }
}

// Per-batch: tanh(maxes) -> softmax -> pooled rQ/rA -> cosine similarity (fp32 out).
__global__ __launch_bounds__(256) void k_final(const u16* __restrict__ QT,
    const u16* __restrict__ AT, const u32* __restrict__ rowmaxE,
    const float* __restrict__ colmax, float* __restrict__ outp){
  __shared__ float roq[128];
  __shared__ float roa[512];
  __shared__ float rqs[FILT];
  __shared__ float ras[FILT];
  __shared__ float sred[2];
  int b = blockIdx.x, tid = threadIdx.x;
  if (tid < 128) roq[tid] = tanhf(decf(rowmaxE[b * LQ + tid]));
  for (int i = tid; i < 512; i += 256) roa[i] = tanhf(colmax[b * LA + i]);
  __syncthreads();
  if (tid == 0){ float m = roq[0]; for (int q = 1; q < 128; q++) m = fmaxf(m, roq[q]); sred[0] = m; }
  if (tid == 1){ float m = roa[0]; for (int a = 1; a < 512; a++) m = fmaxf(m, roa[a]); sred[1] = m; }
  __syncthreads();
  if (tid < 128) roq[tid] = __expf(roq[tid] - sred[0]);
  for (int i = tid; i < 512; i += 256) roa[i] = __expf(roa[i] - sred[1]);
  __syncthreads();
  if (tid == 0){ float s = 0; for (int q = 0; q < 128; q++) s += roq[q]; sred[0] = s; }
  if (tid == 1){ float s = 0; for (int a = 0; a < 512; a++) s += roa[a]; sred[1] = s; }
  __syncthreads();
  if (tid < 128) roq[tid] /= sred[0];
  for (int i = tid; i < 512; i += 256) roa[i] /= sred[1];
  __syncthreads();
  for (int f = tid; f < FILT; f += 256){
    float rq = 0.f, ra = 0.f;
    for (int q = 0; q < LQ; q++) rq += b2f(QT[((size_t)(b * LQ + q)) * FILT + f]) * roq[q];
    for (int a = 0; a < LA; a++) ra += b2f(AT[((size_t)(b * LA + a)) * FILT + f]) * roa[a];
    rqs[f] = rq; ras[f] = ra;
  }
  __syncthreads();
  if (tid == 0){
    float dot = 0, n1 = 0, n2 = 0;
    for (int f = 0; f < FILT; f++){ dot += rqs[f] * ras[f]; n1 += rqs[f] * rqs[f]; n2 += ras[f] * ras[f]; }
    float nq = fmaxf(sqrtf(n1), 1e-8f);
    float na = fmaxf(sqrtf(n2), 1e-8f);
    outp[b] = dot / (nq * na);
  }
}

extern "C" void kernel_launch(void* const* d_in, const int* in_sizes, int n_in,
                              void* d_out, int out_size, void* d_ws, size_t ws_size,
                              hipStream_t stream){
  const int*   qtok = (const int*)d_in[0];
  const int*   atok = (const int*)d_in[1];
  const float* emb  = (const float*)d_in[2];
  const float* cw   = (const float*)d_in[3];
  const float* cb   = (const float*)d_in[4];
  const float* W    = (const float*)d_in[5];
  float* outp = (float*)d_out;

  char* ws = (char*)d_ws;
  size_t off = 0;
  auto alloc = [&](size_t bytes) -> char* {
    char* p = ws + off;
    off = (off + bytes + 255) & ~(size_t)255;
    return p;
  };
  u32*   wTf = (u32*)alloc((size_t)KC * NT * 64 * 16);  // 768 KB, B-fragment order
  u16*   QT  = (u16*)alloc((size_t)BB * LQ * FILT * 2); // 13.1 MB
  u16*   AT  = (u16*)alloc((size_t)BB * LA * FILT * 2); // 52.4 MB
  u16*   T   = (u16*)alloc((size_t)BB * LQ * FILT * 2); // 13.1 MB
  u32*   rme = (u32*)alloc((size_t)BB * LQ * 4);
  float* cm  = (float*)alloc((size_t)BB * LA * 4);

  hipMemsetAsync(rme, 0, (size_t)BB * LQ * 4, stream);  // encodes as -inf sentinel

  k_wt2<<<dim3((KC * NT * 64 + 255) / 256), 256, 0, stream>>>(cw, wTf);
  k_encode_mfma<<<dim3(BB * LQ / MT), 256, 0, stream>>>(qtok, emb, wTf, cb, QT, LQ);
  k_encode_mfma<<<dim3(BB * LA / MT), 256, 0, stream>>>(atok, emb, wTf, cb, AT, LA);
  k_gemmT<<<dim3(LQ / 16, BB), 256, 0, stream>>>(QT, W, T);
  k_scores<<<dim3(LA / 128, BB), 256, 0, stream>>>(T, AT, rme, cm);
  k_final<<<BB, 256, 0, stream>>>(QT, AT, rme, cm, outp);
}

// Round 4
// 569.540 us; speedup vs baseline: 6.7940x; 2.0362x over previous
//
#include <hip/hip_runtime.h>
#include <hip/hip_bf16.h>

// Problem dims (AttentivePoolingNetwork)
#define BB   128
#define LQ   128
#define LA   512
#define EMBD 300
#define FILT 400
#define KW   3

#define NT   25    // n-tiles of 16 (400)
#define KC   30    // k-chunks of 32 for encode (3 emb-blocks padded to 320 each)
#define KCF  13    // k-chunks of 32 over FILT=400 (12 full + 1 peeled half)
#define MT   64    // rows per block (encode / gemmT)

typedef unsigned short u16;
typedef unsigned int   u32;
typedef __attribute__((ext_vector_type(4))) int    i32x4;
typedef __attribute__((ext_vector_type(4))) float  f32x4;
typedef __attribute__((ext_vector_type(8))) __bf16 bf16x8;

__device__ __forceinline__ float b2f(u16 h){ return __uint_as_float(((u32)h) << 16); }
__device__ __forceinline__ u16 f2b(float f){
  u32 u = __float_as_uint(f);
  u32 r = (u + 0x7FFFu + ((u >> 16) & 1u)) >> 16;   // RNE
  return (u16)r;
}
// order-preserving float -> uint encoding (for atomicMax on floats)
__device__ __forceinline__ u32 encf(float f){
  u32 u = __float_as_uint(f);
  return (u & 0x80000000u) ? ~u : (u | 0x80000000u);
}
__device__ __forceinline__ float decf(u32 k){
  u32 u = (k & 0x80000000u) ? (k ^ 0x80000000u) : ~k;
  return __uint_as_float(u);
}
__device__ __forceinline__ bf16x8 bzero(){
  i32x4 z; z.x = 0; z.y = 0; z.z = 0; z.w = 0;
  return __builtin_bit_cast(bf16x8, z);
}

// conv_w [F][E][K] fp32 -> wTf in MFMA B-fragment order:
// wTf[kc][nt][lane][j] (bf16), element = B[k'=kc*32+quad*8+j][n=nt*16+(lane&15)]
// where k' -> (kk = k'/320, e = k'%320), value = (e<300) ? conv_w[n][e][kk] : 0.
__global__ void k_wt2(const float* __restrict__ cw, u32* __restrict__ wTf){
  int idx = blockIdx.x * 256 + threadIdx.x;
  if (idx >= KC * NT * 64) return;
  int kc  = idx / (NT * 64);
  int rem = idx - kc * (NT * 64);
  int nt  = rem >> 6;
  int lane = rem & 63;
  int n = nt * 16 + (lane & 15);
  int quad = lane >> 4;
  u32 pack[4];
  #pragma unroll
  for (int d = 0; d < 4; d++){
    u16 h[2];
    #pragma unroll
    for (int s = 0; s < 2; s++){
      int kp = kc * 32 + quad * 8 + 2 * d + s;
      int kk = kp / 320, e = kp - kk * 320;
      float v = (e < EMBD) ? cw[(size_t)n * (EMBD * KW) + e * KW + kk] : 0.f;
      h[s] = f2b(v);
    }
    pack[d] = (u32)h[0] | ((u32)h[1] << 16);
  }
  i32x4 out4; out4.x = pack[0]; out4.y = pack[1]; out4.z = pack[2]; out4.w = pack[3];
  *((i32x4*)wTf + idx) = out4;
}

// W [f][g] fp32 -> wF B-fragment order: wF[kc][nt][lane][j],
// element = B[k=f=kc*32+quad*8+j][n=g=nt*16+(lane&15)], zero for f>=400.
__global__ void k_wf(const float* __restrict__ W, u32* __restrict__ wF){
  int idx = blockIdx.x * 256 + threadIdx.x;
  if (idx >= KCF * NT * 64) return;
  int kc  = idx / (NT * 64);
  int rem = idx - kc * (NT * 64);
  int nt  = rem >> 6;
  int lane = rem & 63;
  int n = nt * 16 + (lane & 15);
  int quad = lane >> 4;
  u32 pack[4];
  #pragma unroll
  for (int d = 0; d < 4; d++){
    u16 h[2];
    #pragma unroll
    for (int s = 0; s < 2; s++){
      int k = kc * 32 + quad * 8 + 2 * d + s;
      float v = (k < FILT) ? W[(size_t)k * FILT + n] : 0.f;
      h[s] = f2b(v);
    }
    pack[d] = (u32)h[0] | ((u32)h[1] << 16);
  }
  i32x4 out4; out4.x = pack[0]; out4.y = pack[1]; out4.z = pack[2]; out4.w = pack[3];
  *((i32x4*)wF + idx) = out4;
}

// Embed + conv1d(pad=1) as MFMA GEMM. Barrier-free K-loop:
// A (gathered emb rows) in LDS; B-frags loaded per-lane direct from global wTf.
// grid = (B*L)/64 blocks, 256 threads (4 waves). Block: 64 rows x 400 cols.
__global__ __launch_bounds__(256) void k_encode_mfma(const int* __restrict__ toks,
    const float* __restrict__ emb, const u32* __restrict__ wTf,
    const float* __restrict__ bias, u16* __restrict__ out, int L){
  __shared__ u16 At[66 * 328];   // emb tile, bf16, stride 328

  const int tid  = threadIdx.x;
  const int w    = tid >> 6;
  const int lane = tid & 63;
  const int col  = lane & 15;
  const int quad = lane >> 4;
  const int row0 = blockIdx.x * MT;
  const int b    = row0 / L;
  const int l0   = row0 - b * L;

  for (int i = tid; i < 66 * 328 / 2; i += 256) ((u32*)At)[i] = 0u;
  __syncthreads();
  for (int i = tid; i < 66 * 75; i += 256){
    int r = i / 75, c4 = i - r * 75;
    int pos = l0 - 1 + r;
    if ((unsigned)pos < (unsigned)L){
      int t = toks[b * L + pos];
      float4 v = *((const float4*)(emb + (size_t)t * EMBD) + c4);
      u32 p0 = (u32)f2b(v.x) | ((u32)f2b(v.y) << 16);
      u32 p1 = (u32)f2b(v.z) | ((u32)f2b(v.w) << 16);
      int di = (r * 328 + c4 * 4) >> 1;
      ((u32*)At)[di]     = p0;
      ((u32*)At)[di + 1] = p1;
    }
  }

  f32x4 acc[7][4];
  #pragma unroll
  for (int j = 0; j < 7; j++)
    #pragma unroll
    for (int mf = 0; mf < 4; mf++)
      acc[j][mf] = (f32x4){0.f, 0.f, 0.f, 0.f};

  __syncthreads();

  for (int kc = 0; kc < KC; kc++){
    int kk = kc / 10;
    int e0 = (kc - kk * 10) * 32;
    bf16x8 afr[4];
    {
      int ebase = e0 + quad * 8;
      #pragma unroll
      for (int mf = 0; mf < 4; mf++){
        int r = mf * 16 + col + kk;
        afr[mf] = __builtin_bit_cast(bf16x8, *(const i32x4*)(At + r * 328 + ebase));
      }
    }
    const i32x4* bsrc = (const i32x4*)wTf + (size_t)kc * (NT * 64) + lane;
    #pragma unroll
    for (int j = 0; j < 7; j++){
      int nt = w + 4 * j;
      if (nt < NT){
        bf16x8 bfr = __builtin_bit_cast(bf16x8, bsrc[nt * 64]);
        #pragma unroll
        for (int mf = 0; mf < 4; mf++)
          acc[j][mf] = __builtin_amdgcn_mfma_f32_16x16x32_bf16(afr[mf], bfr, acc[j][mf], 0, 0, 0);
      }
    }
  }

  // epilogue: + bias, bf16 store. C/D: col=lane&15, row=quad*4+reg.
  #pragma unroll
  for (int j = 0; j < 7; j++){
    int nt = w + 4 * j;
    if (nt < NT){
      int n = nt * 16 + col;
      float bv = bias[n];
      #pragma unroll
      for (int mf = 0; mf < 4; mf++){
        int rbase = row0 + mf * 16 + quad * 4;
        #pragma unroll
        for (int r = 0; r < 4; r++)
          out[(size_t)(rbase + r) * FILT + n] = f2b(acc[j][mf][r] + bv);
      }
    }
  }
}

// T = QT * W as MFMA GEMM, barrier-free, no LDS.
// A-frags direct from QT rows (bf16 row-major), B-frags from wF.
// K=400: kc 0..11 full, kc=12 peeled (quads 2,3 -> zero).
// grid = (BB*LQ)/64 blocks, 256 threads.
__global__ __launch_bounds__(256) void k_gemmT2(const u16* __restrict__ QT,
    const u32* __restrict__ wF, u16* __restrict__ T){
  const int tid  = threadIdx.x;
  const int w    = tid >> 6;
  const int lane = tid & 63;
  const int col  = lane & 15;
  const int quad = lane >> 4;
  const int row0 = blockIdx.x * MT;

  f32x4 acc[7][4];
  #pragma unroll
  for (int j = 0; j < 7; j++)
    #pragma unroll
    for (int mf = 0; mf < 4; mf++)
      acc[j][mf] = (f32x4){0.f, 0.f, 0.f, 0.f};

  for (int kc = 0; kc < KCF; kc++){
    bf16x8 afr[4];
    #pragma unroll
    for (int mf = 0; mf < 4; mf++){
      if (kc < 12 || quad < 2)
        afr[mf] = __builtin_bit_cast(bf16x8,
          *(const i32x4*)(QT + (size_t)(row0 + mf * 16 + col) * FILT + kc * 32 + quad * 8));
      else
        afr[mf] = bzero();
    }
    const i32x4* bsrc = (const i32x4*)wF + (size_t)kc * (NT * 64) + lane;
    #pragma unroll
    for (int j = 0; j < 7; j++){
      int nt = w + 4 * j;
      if (nt < NT){
        bf16x8 bfr = __builtin_bit_cast(bf16x8, bsrc[nt * 64]);
        #pragma unroll
        for (int mf = 0; mf < 4; mf++)
          acc[j][mf] = __builtin_amdgcn_mfma_f32_16x16x32_bf16(afr[mf], bfr, acc[j][mf], 0, 0, 0);
      }
    }
  }

  #pragma unroll
  for (int j = 0; j < 7; j++){
    int nt = w + 4 * j;
    if (nt < NT){
      int n = nt * 16 + col;
      #pragma unroll
      for (int mf = 0; mf < 4; mf++){
        int rbase = row0 + mf * 16 + quad * 4;
        #pragma unroll
        for (int r = 0; r < 4; r++)
          T[(size_t)(rbase + r) * FILT + n] = f2b(acc[j][mf][r]);
      }
    }
  }
}

// Scores S[q][a] = sum_g T[b][q][g] * AT[b][a][g] via MFMA; row/col maxes only
// (tanh monotonic -> applied later). grid (LA/128, BB), 256 threads.
// Block: 128 q x 128 a. Wave w: q-tiles {2w,2w+1} x all 8 a-tiles.
__global__ __launch_bounds__(256) void k_scores2(const u16* __restrict__ T,
    const u16* __restrict__ AT, u32* __restrict__ rowmaxE, float* __restrict__ colmax){
  __shared__ float rpart[128][17];
  __shared__ float cpart[128][17];
  const int tid  = threadIdx.x;
  const int w    = tid >> 6;
  const int lane = tid & 63;
  const int col  = lane & 15;
  const int quad = lane >> 4;
  const int b    = blockIdx.y;
  const int a0   = blockIdx.x * 128;

  f32x4 acc[2][8];
  #pragma unroll
  for (int i = 0; i < 2; i++)
    #pragma unroll
    for (int j = 0; j < 8; j++)
      acc[i][j] = (f32x4){0.f, 0.f, 0.f, 0.f};

  for (int kc = 0; kc < KCF; kc++){
    bf16x8 afr[2], bfr[8];
    bool live = (kc < 12) || (quad < 2);
    #pragma unroll
    for (int i = 0; i < 2; i++)
      afr[i] = live ? __builtin_bit_cast(bf16x8,
          *(const i32x4*)(T + (size_t)(b * LQ + (2 * w + i) * 16 + col) * FILT + kc * 32 + quad * 8))
        : bzero();
    #pragma unroll
    for (int j = 0; j < 8; j++)
      bfr[j] = live ? __builtin_bit_cast(bf16x8,
          *(const i32x4*)(AT + (size_t)(b * LA + a0 + j * 16 + col) * FILT + kc * 32 + quad * 8))
        : bzero();
    #pragma unroll
    for (int i = 0; i < 2; i++)
      #pragma unroll
      for (int j = 0; j < 8; j++)
        acc[i][j] = __builtin_amdgcn_mfma_f32_16x16x32_bf16(afr[i], bfr[j], acc[i][j], 0, 0, 0);
  }

  // row partials: q = (2w+i)*16 + quad*4 + r, col index = a-lane
  #pragma unroll
  for (int i = 0; i < 2; i++)
    #pragma unroll
    for (int r = 0; r < 4; r++){
      float m = acc[i][0][r];
      #pragma unroll
      for (int j = 1; j < 8; j++) m = fmaxf(m, acc[i][j][r]);
      rpart[(2 * w + i) * 16 + quad * 4 + r][col] = m;
    }
  // col partials: a = j*16 + col, slot = w*4+quad
  #pragma unroll
  for (int j = 0; j < 8; j++){
    float m = acc[0][j][0];
    #pragma unroll
    for (int i = 0; i < 2; i++)
      #pragma unroll
      for (int r = 0; r < 4; r++) m = fmaxf(m, acc[i][j][r]);
    cpart[j * 16 + col][w * 4 + quad] = m;
  }
  __syncthreads();
  if (tid < 128){
    float m = rpart[tid][0];
    #pragma unroll
    for (int g = 1; g < 16; g++) m = fmaxf(m, rpart[tid][g]);
    atomicMax(&rowmaxE[b * LQ + tid], encf(m));
    float m2 = cpart[tid][0];
    #pragma unroll
    for (int g = 1; g < 16; g++) m2 = fmaxf(m2, cpart[tid][g]);
    colmax[b * LA + a0 + tid] = m2;
  }
}

// Per-batch: tanh(maxes) -> softmax -> pooled rQ/rA -> cosine similarity (fp32 out).
__global__ __launch_bounds__(256) void k_final(const u16* __restrict__ QT,
    const u16* __restrict__ AT, const u32* __restrict__ rowmaxE,
    const float* __restrict__ colmax, float* __restrict__ outp){
  __shared__ float roq[128];
  __shared__ float roa[512];
  __shared__ float rqs[FILT];
  __shared__ float ras[FILT];
  __shared__ float sred[2];
  int b = blockIdx.x, tid = threadIdx.x;
  if (tid < 128) roq[tid] = tanhf(decf(rowmaxE[b * LQ + tid]));
  for (int i = tid; i < 512; i += 256) roa[i] = tanhf(colmax[b * LA + i]);
  __syncthreads();
  if (tid == 0){ float m = roq[0]; for (int q = 1; q < 128; q++) m = fmaxf(m, roq[q]); sred[0] = m; }
  if (tid == 1){ float m = roa[0]; for (int a = 1; a < 512; a++) m = fmaxf(m, roa[a]); sred[1] = m; }
  __syncthreads();
  if (tid < 128) roq[tid] = __expf(roq[tid] - sred[0]);
  for (int i = tid; i < 512; i += 256) roa[i] = __expf(roa[i] - sred[1]);
  __syncthreads();
  if (tid == 0){ float s = 0; for (int q = 0; q < 128; q++) s += roq[q]; sred[0] = s; }
  if (tid == 1){ float s = 0; for (int a = 0; a < 512; a++) s += roa[a]; sred[1] = s; }
  __syncthreads();
  if (tid < 128) roq[tid] /= sred[0];
  for (int i = tid; i < 512; i += 256) roa[i] /= sred[1];
  __syncthreads();
  for (int f = tid; f < FILT; f += 256){
    float rq = 0.f, ra = 0.f;
    for (int q = 0; q < LQ; q++) rq += b2f(QT[((size_t)(b * LQ + q)) * FILT + f]) * roq[q];
    for (int a = 0; a < LA; a++) ra += b2f(AT[((size_t)(b * LA + a)) * FILT + f]) * roa[a];
    rqs[f] = rq; ras[f] = ra;
  }
  __syncthreads();
  if (tid == 0){
    float dot = 0, n1 = 0, n2 = 0;
    for (int f = 0; f < FILT; f++){ dot += rqs[f] * ras[f]; n1 += rqs[f] * rqs[f]; n2 += ras[f] * ras[f]; }
    float nq = fmaxf(sqrtf(n1), 1e-8f);
    float na = fmaxf(sqrtf(n2), 1e-8f);
    outp[b] = dot / (nq * na);
  }
}

extern "C" void kernel_launch(void* const* d_in, const int* in_sizes, int n_in,
                              void* d_out, int out_size, void* d_ws, size_t ws_size,
                              hipStream_t stream){
  const int*   qtok = (const int*)d_in[0];
  const int*   atok = (const int*)d_in[1];
  const float* emb  = (const float*)d_in[2];
  const float* cw   = (const float*)d_in[3];
  const float* cb   = (const float*)d_in[4];
  const float* W    = (const float*)d_in[5];
  float* outp = (float*)d_out;

  char* ws = (char*)d_ws;
  size_t off = 0;
  auto alloc = [&](size_t bytes) -> char* {
    char* p = ws + off;
    off = (off + bytes + 255) & ~(size_t)255;
    return p;
  };
  u32*   wTf = (u32*)alloc((size_t)KC * NT * 64 * 16);   // 768 KB
  u32*   wF  = (u32*)alloc((size_t)KCF * NT * 64 * 16);  // 333 KB
  u16*   QT  = (u16*)alloc((size_t)BB * LQ * FILT * 2);  // 13.1 MB
  u16*   AT  = (u16*)alloc((size_t)BB * LA * FILT * 2);  // 52.4 MB
  u16*   T   = (u16*)alloc((size_t)BB * LQ * FILT * 2);  // 13.1 MB
  u32*   rme = (u32*)alloc((size_t)BB * LQ * 4);
  float* cm  = (float*)alloc((size_t)BB * LA * 4);

  hipMemsetAsync(rme, 0, (size_t)BB * LQ * 4, stream);   // < encf(any finite)

  k_wt2<<<dim3((KC * NT * 64 + 255) / 256), 256, 0, stream>>>(cw, wTf);
  k_wf<<<dim3((KCF * NT * 64 + 255) / 256), 256, 0, stream>>>(W, wF);
  k_encode_mfma<<<dim3(BB * LQ / MT), 256, 0, stream>>>(qtok, emb, wTf, cb, QT, LQ);
  k_encode_mfma<<<dim3(BB * LA / MT), 256, 0, stream>>>(atok, emb, wTf, cb, AT, LA);
  k_gemmT2<<<dim3(BB * LQ / MT), 256, 0, stream>>>(QT, wF, T);
  k_scores2<<<dim3(LA / 128, BB), 256, 0, stream>>>(T, AT, rme, cm);
  k_final<<<BB, 256, 0, stream>>>(QT, AT, rme, cm, outp);
}

// Round 5
// 323.187 us; speedup vs baseline: 11.9728x; 1.7623x over previous
//
#include <hip/hip_runtime.h>
#include <hip/hip_bf16.h>

// Problem dims (AttentivePoolingNetwork)
#define BB   128
#define LQ   128
#define LA   512
#define EMBD 300
#define FILT 400
#define KW   3

#define NT   25    // n-tiles of 16 (400)
#define KC   30    // k-chunks of 32 for encode (3 emb-blocks padded to 320 each)
#define KCF  13    // k-chunks of 32 over FILT=400 (12 full + 1 zero-padded)
#define MT   32    // rows per block (encode / gemmT)

typedef unsigned short u16;
typedef unsigned int   u32;
typedef __attribute__((ext_vector_type(4))) int    i32x4;
typedef __attribute__((ext_vector_type(4))) float  f32x4;
typedef __attribute__((ext_vector_type(8))) __bf16 bf16x8;

__device__ __forceinline__ float b2f(u16 h){ return __uint_as_float(((u32)h) << 16); }
__device__ __forceinline__ u16 f2b(float f){
  u32 u = __float_as_uint(f);
  u32 r = (u + 0x7FFFu + ((u >> 16) & 1u)) >> 16;   // RNE
  return (u16)r;
}
__device__ __forceinline__ u32 encf(float f){
  u32 u = __float_as_uint(f);
  return (u & 0x80000000u) ? ~u : (u | 0x80000000u);
}
__device__ __forceinline__ float decf(u32 k){
  u32 u = (k & 0x80000000u) ? (k ^ 0x80000000u) : ~k;
  return __uint_as_float(u);
}
__device__ __forceinline__ bf16x8 bzero(){
  i32x4 z; z.x = 0; z.y = 0; z.z = 0; z.w = 0;
  return __builtin_bit_cast(bf16x8, z);
}

// conv_w [F][E][K] fp32 -> wTf in MFMA B-fragment order:
// wTf[kc][nt][lane][j] (bf16), element = B[k'=kc*32+quad*8+j][n=nt*16+(lane&15)]
// k' -> (kk=k'/320, e=k'%320); value = (e<300) ? conv_w[n][e][kk] : 0.
__global__ void k_wt2(const float* __restrict__ cw, u32* __restrict__ wTf){
  int idx = blockIdx.x * 256 + threadIdx.x;
  if (idx >= KC * NT * 64) return;
  int kc  = idx / (NT * 64);
  int rem = idx - kc * (NT * 64);
  int nt  = rem >> 6;
  int lane = rem & 63;
  int n = nt * 16 + (lane & 15);
  int quad = lane >> 4;
  u32 pack[4];
  #pragma unroll
  for (int d = 0; d < 4; d++){
    u16 h[2];
    #pragma unroll
    for (int s = 0; s < 2; s++){
      int kp = kc * 32 + quad * 8 + 2 * d + s;
      int kk = kp / 320, e = kp - kk * 320;
      float v = (e < EMBD) ? cw[(size_t)n * (EMBD * KW) + e * KW + kk] : 0.f;
      h[s] = f2b(v);
    }
    pack[d] = (u32)h[0] | ((u32)h[1] << 16);
  }
  i32x4 out4; out4.x = pack[0]; out4.y = pack[1]; out4.z = pack[2]; out4.w = pack[3];
  *((i32x4*)wTf + idx) = out4;
}

// W [f][g] fp32 -> wF B-fragment order (zero for f>=400).
__global__ void k_wf(const float* __restrict__ W, u32* __restrict__ wF){
  int idx = blockIdx.x * 256 + threadIdx.x;
  if (idx >= KCF * NT * 64) return;
  int kc  = idx / (NT * 64);
  int rem = idx - kc * (NT * 64);
  int nt  = rem >> 6;
  int lane = rem & 63;
  int n = nt * 16 + (lane & 15);
  int quad = lane >> 4;
  u32 pack[4];
  #pragma unroll
  for (int d = 0; d < 4; d++){
    u16 h[2];
    #pragma unroll
    for (int s = 0; s < 2; s++){
      int k = kc * 32 + quad * 8 + 2 * d + s;
      float v = (k < FILT) ? W[(size_t)k * FILT + n] : 0.f;
      h[s] = f2b(v);
    }
    pack[d] = (u32)h[0] | ((u32)h[1] << 16);
  }
  i32x4 out4; out4.x = pack[0]; out4.y = pack[1]; out4.z = pack[2]; out4.w = pack[3];
  *((i32x4*)wF + idx) = out4;
}

// Embed + conv1d(pad=1) as MFMA GEMM, 32 rows/block, reg-double-buffered B.
// A (gathered emb rows) in LDS; B-frags per-lane direct from global wTf with
// 1-deep register prefetch. grid = (B*L)/32 blocks, 256 threads (4 waves).
// Wave w: nt = {w, w+4, ..., w+20} (+ nt=24 for wave 0).
__global__ __launch_bounds__(256) void k_encode_mfma(const int* __restrict__ toks,
    const float* __restrict__ emb, const u32* __restrict__ wTf,
    const float* __restrict__ bias, u16* __restrict__ out, int L){
  __shared__ u16 At[34 * 328];   // 32+2 halo rows, stride 328

  const int tid  = threadIdx.x;
  const int w    = tid >> 6;
  const int lane = tid & 63;
  const int col  = lane & 15;
  const int quad = lane >> 4;
  const int row0 = blockIdx.x * MT;
  const int b    = row0 / L;
  const int l0   = row0 - b * L;

  for (int i = tid; i < 34 * 328 / 2; i += 256) ((u32*)At)[i] = 0u;
  __syncthreads();
  for (int i = tid; i < 34 * 75; i += 256){
    int r = i / 75, c4 = i - r * 75;
    int pos = l0 - 1 + r;
    if ((unsigned)pos < (unsigned)L){
      int t = toks[b * L + pos];
      float4 v = *((const float4*)(emb + (size_t)t * EMBD) + c4);
      u32 p0 = (u32)f2b(v.x) | ((u32)f2b(v.y) << 16);
      u32 p1 = (u32)f2b(v.z) | ((u32)f2b(v.w) << 16);
      int di = (r * 328 + c4 * 4) >> 1;
      ((u32*)At)[di]     = p0;
      ((u32*)At)[di + 1] = p1;
    }
  }

  f32x4 acc[7][2];
  #pragma unroll
  for (int j = 0; j < 7; j++)
    #pragma unroll
    for (int mf = 0; mf < 2; mf++)
      acc[j][mf] = (f32x4){0.f, 0.f, 0.f, 0.f};

  __syncthreads();

  const i32x4* bbase = (const i32x4*)wTf + lane;
  i32x4 Bb[2][7];
  {
    const i32x4* s = bbase;
    #pragma unroll
    for (int j = 0; j < 6; j++) Bb[0][j] = s[(w + 4 * j) * 64];
    if (w == 0) Bb[0][6] = s[24 * 64];
  }
  #pragma unroll
  for (int kc = 0; kc < KC; kc++){
    const int cur = kc & 1;
    if (kc + 1 < KC){
      const i32x4* s = bbase + (size_t)(kc + 1) * (NT * 64);
      #pragma unroll
      for (int j = 0; j < 6; j++) Bb[cur ^ 1][j] = s[(w + 4 * j) * 64];
      if (w == 0) Bb[cur ^ 1][6] = s[24 * 64];
    }
    const int kk = kc / 10, e0 = (kc - kk * 10) * 32;
    const int ebase = e0 + quad * 8;
    bf16x8 a0 = __builtin_bit_cast(bf16x8, *(const i32x4*)(At + (col + kk) * 328 + ebase));
    bf16x8 a1 = __builtin_bit_cast(bf16x8, *(const i32x4*)(At + (16 + col + kk) * 328 + ebase));
    #pragma unroll
    for (int j = 0; j < 6; j++){
      bf16x8 bf = __builtin_bit_cast(bf16x8, Bb[cur][j]);
      acc[j][0] = __builtin_amdgcn_mfma_f32_16x16x32_bf16(a0, bf, acc[j][0], 0, 0, 0);
      acc[j][1] = __builtin_amdgcn_mfma_f32_16x16x32_bf16(a1, bf, acc[j][1], 0, 0, 0);
    }
    if (w == 0){
      bf16x8 bf = __builtin_bit_cast(bf16x8, Bb[cur][6]);
      acc[6][0] = __builtin_amdgcn_mfma_f32_16x16x32_bf16(a0, bf, acc[6][0], 0, 0, 0);
      acc[6][1] = __builtin_amdgcn_mfma_f32_16x16x32_bf16(a1, bf, acc[6][1], 0, 0, 0);
    }
  }

  // epilogue: + bias, bf16 store. C/D: col=lane&15, row=quad*4+reg.
  #pragma unroll
  for (int j = 0; j < 7; j++){
    if (j == 6 && w != 0) continue;      // wave-uniform
    int nt = (j < 6) ? (w + 4 * j) : 24;
    int n = nt * 16 + col;
    float bv = bias[n];
    #pragma unroll
    for (int mf = 0; mf < 2; mf++){
      int rbase = row0 + mf * 16 + quad * 4;
      #pragma unroll
      for (int r = 0; r < 4; r++)
        out[(size_t)(rbase + r) * FILT + n] = f2b(acc[j][mf][r] + bv);
    }
  }
}

// T = QT * W, MFMA, no LDS, reg-double-buffered A and B.
// No edge masking needed: wF zero-pads k>=400 and any OOB A-read lands in AT
// (finite bf16), garbage*0 = 0. grid = BB*LQ/32 blocks.
__global__ __launch_bounds__(256) void k_gemmT2(const u16* __restrict__ QT,
    const u32* __restrict__ wF, u16* __restrict__ T){
  const int tid  = threadIdx.x;
  const int w    = tid >> 6;
  const int lane = tid & 63;
  const int col  = lane & 15;
  const int quad = lane >> 4;
  const int row0 = blockIdx.x * MT;

  f32x4 acc[7][2];
  #pragma unroll
  for (int j = 0; j < 7; j++)
    #pragma unroll
    for (int mf = 0; mf < 2; mf++)
      acc[j][mf] = (f32x4){0.f, 0.f, 0.f, 0.f};

  const u16* arow0 = QT + (size_t)(row0 + col) * FILT;
  const u16* arow1 = QT + (size_t)(row0 + 16 + col) * FILT;
  const i32x4* bbase = (const i32x4*)wF + lane;

  i32x4 Ab[2][2];
  i32x4 Bb[2][7];
  {
    int off = quad * 8;
    Ab[0][0] = *(const i32x4*)(arow0 + off);
    Ab[0][1] = *(const i32x4*)(arow1 + off);
    #pragma unroll
    for (int j = 0; j < 6; j++) Bb[0][j] = bbase[(w + 4 * j) * 64];
    if (w == 0) Bb[0][6] = bbase[24 * 64];
  }
  #pragma unroll
  for (int kc = 0; kc < KCF; kc++){
    const int cur = kc & 1;
    if (kc + 1 < KCF){
      int off = (kc + 1) * 32 + quad * 8;
      Ab[cur ^ 1][0] = *(const i32x4*)(arow0 + off);
      Ab[cur ^ 1][1] = *(const i32x4*)(arow1 + off);
      const i32x4* s = bbase + (size_t)(kc + 1) * (NT * 64);
      #pragma unroll
      for (int j = 0; j < 6; j++) Bb[cur ^ 1][j] = s[(w + 4 * j) * 64];
      if (w == 0) Bb[cur ^ 1][6] = s[24 * 64];
    }
    bf16x8 a0 = __builtin_bit_cast(bf16x8, Ab[cur][0]);
    bf16x8 a1 = __builtin_bit_cast(bf16x8, Ab[cur][1]);
    #pragma unroll
    for (int j = 0; j < 6; j++){
      bf16x8 bf = __builtin_bit_cast(bf16x8, Bb[cur][j]);
      acc[j][0] = __builtin_amdgcn_mfma_f32_16x16x32_bf16(a0, bf, acc[j][0], 0, 0, 0);
      acc[j][1] = __builtin_amdgcn_mfma_f32_16x16x32_bf16(a1, bf, acc[j][1], 0, 0, 0);
    }
    if (w == 0){
      bf16x8 bf = __builtin_bit_cast(bf16x8, Bb[cur][6]);
      acc[6][0] = __builtin_amdgcn_mfma_f32_16x16x32_bf16(a0, bf, acc[6][0], 0, 0, 0);
      acc[6][1] = __builtin_amdgcn_mfma_f32_16x16x32_bf16(a1, bf, acc[6][1], 0, 0, 0);
    }
  }

  #pragma unroll
  for (int j = 0; j < 7; j++){
    if (j == 6 && w != 0) continue;
    int nt = (j < 6) ? (w + 4 * j) : 24;
    int n = nt * 16 + col;
    #pragma unroll
    for (int mf = 0; mf < 2; mf++){
      int rbase = row0 + mf * 16 + quad * 4;
      #pragma unroll
      for (int r = 0; r < 4; r++)
        T[(size_t)(rbase + r) * FILT + n] = f2b(acc[j][mf][r]);
    }
  }
}

// Scores S[q][a] = sum_g T[q][g]*AT[a][g] via MFMA; row/col maxes only.
// Reg-double-buffered loads; T-side zero-select for the k>=400 tail.
// grid (LA/128, BB). Wave w: q-tiles {2w,2w+1} x 8 a-tiles.
__global__ __launch_bounds__(256) void k_scores2(const u16* __restrict__ T,
    const u16* __restrict__ AT, u32* __restrict__ rowmaxE, float* __restrict__ colmax){
  __shared__ float rpart[128][17];
  __shared__ float cpart[128][17];
  const int tid  = threadIdx.x;
  const int w    = tid >> 6;
  const int lane = tid & 63;
  const int col  = lane & 15;
  const int quad = lane >> 4;
  const int b    = blockIdx.y;
  const int a0   = blockIdx.x * 128;

  f32x4 acc[2][8];
  #pragma unroll
  for (int i = 0; i < 2; i++)
    #pragma unroll
    for (int j = 0; j < 8; j++)
      acc[i][j] = (f32x4){0.f, 0.f, 0.f, 0.f};

  const u16* tr0 = T  + (size_t)(b * LQ + (2 * w) * 16 + col) * FILT;
  const u16* tr1 = T  + (size_t)(b * LQ + (2 * w + 1) * 16 + col) * FILT;
  const u16* ar  = AT + (size_t)(b * LA + a0 + col) * FILT;

  i32x4 Abuf[2][2], Bbuf[2][8];
  {
    int off = quad * 8;
    Abuf[0][0] = *(const i32x4*)(tr0 + off);
    Abuf[0][1] = *(const i32x4*)(tr1 + off);
    #pragma unroll
    for (int j = 0; j < 8; j++)
      Bbuf[0][j] = *(const i32x4*)(ar + (size_t)(j * 16) * FILT + off);
  }
  #pragma unroll
  for (int kc = 0; kc < KCF; kc++){
    const int cur = kc & 1;
    if (kc + 1 < KCF){
      int off = (kc + 1) * 32 + quad * 8;
      Abuf[cur ^ 1][0] = *(const i32x4*)(tr0 + off);
      Abuf[cur ^ 1][1] = *(const i32x4*)(tr1 + off);
      #pragma unroll
      for (int j = 0; j < 8; j++)
        Bbuf[cur ^ 1][j] = *(const i32x4*)(ar + (size_t)(j * 16) * FILT + off);
    }
    const bool live = (kc < 12) || (quad < 2);
    bf16x8 a0 = live ? __builtin_bit_cast(bf16x8, Abuf[cur][0]) : bzero();
    bf16x8 a1 = live ? __builtin_bit_cast(bf16x8, Abuf[cur][1]) : bzero();
    #pragma unroll
    for (int j = 0; j < 8; j++){
      bf16x8 bf = __builtin_bit_cast(bf16x8, Bbuf[cur][j]);
      acc[0][j] = __builtin_amdgcn_mfma_f32_16x16x32_bf16(a0, bf, acc[0][j], 0, 0, 0);
      acc[1][j] = __builtin_amdgcn_mfma_f32_16x16x32_bf16(a1, bf, acc[1][j], 0, 0, 0);
    }
  }

  #pragma unroll
  for (int i = 0; i < 2; i++)
    #pragma unroll
    for (int r = 0; r < 4; r++){
      float m = acc[i][0][r];
      #pragma unroll
      for (int j = 1; j < 8; j++) m = fmaxf(m, acc[i][j][r]);
      rpart[(2 * w + i) * 16 + quad * 4 + r][col] = m;
    }
  #pragma unroll
  for (int j = 0; j < 8; j++){
    float m = acc[0][j][0];
    #pragma unroll
    for (int i = 0; i < 2; i++)
      #pragma unroll
      for (int r = 0; r < 4; r++) m = fmaxf(m, acc[i][j][r]);
    cpart[j * 16 + col][w * 4 + quad] = m;
  }
  __syncthreads();
  if (tid < 128){
    float m = rpart[tid][0];
    #pragma unroll
    for (int g = 1; g < 16; g++) m = fmaxf(m, rpart[tid][g]);
    atomicMax(&rowmaxE[b * LQ + tid], encf(m));
    float m2 = cpart[tid][0];
    #pragma unroll
    for (int g = 1; g < 16; g++) m2 = fmaxf(m2, cpart[tid][g]);
    colmax[b * LA + a0 + tid] = m2;
  }
}

// Per-batch: tanh(maxes) -> softmax -> pooled rQ/rA -> cosine similarity (fp32 out).
__global__ __launch_bounds__(256) void k_final(const u16* __restrict__ QT,
    const u16* __restrict__ AT, const u32* __restrict__ rowmaxE,
    const float* __restrict__ colmax, float* __restrict__ outp){
  __shared__ float roq[128];
  __shared__ float roa[512];
  __shared__ float rqs[FILT];
  __shared__ float ras[FILT];
  __shared__ float sred[2];
  int b = blockIdx.x, tid = threadIdx.x;
  if (tid < 128) roq[tid] = tanhf(decf(rowmaxE[b * LQ + tid]));
  for (int i = tid; i < 512; i += 256) roa[i] = tanhf(colmax[b * LA + i]);
  __syncthreads();
  if (tid == 0){ float m = roq[0]; for (int q = 1; q < 128; q++) m = fmaxf(m, roq[q]); sred[0] = m; }
  if (tid == 1){ float m = roa[0]; for (int a = 1; a < 512; a++) m = fmaxf(m, roa[a]); sred[1] = m; }
  __syncthreads();
  if (tid < 128) roq[tid] = __expf(roq[tid] - sred[0]);
  for (int i = tid; i < 512; i += 256) roa[i] = __expf(roa[i] - sred[1]);
  __syncthreads();
  if (tid == 0){ float s = 0; for (int q = 0; q < 128; q++) s += roq[q]; sred[0] = s; }
  if (tid == 1){ float s = 0; for (int a = 0; a < 512; a++) s += roa[a]; sred[1] = s; }
  __syncthreads();
  if (tid < 128) roq[tid] /= sred[0];
  for (int i = tid; i < 512; i += 256) roa[i] /= sred[1];
  __syncthreads();
  // pooled vectors, u32-paired loads (2 filters per thread)
  for (int f2 = tid; f2 < FILT / 2; f2 += 256){
    float rq0 = 0.f, rq1 = 0.f, ra0 = 0.f, ra1 = 0.f;
    const u32* qp = (const u32*)(QT + (size_t)(b * LQ) * FILT) + f2;
    const u32* ap = (const u32*)(AT + (size_t)(b * LA) * FILT) + f2;
    for (int q = 0; q < LQ; q++){
      u32 u = qp[q * (FILT / 2)];
      float wq = roq[q];
      rq0 += __uint_as_float(u << 16) * wq;
      rq1 += __uint_as_float(u & 0xFFFF0000u) * wq;
    }
    for (int a = 0; a < LA; a++){
      u32 u = ap[a * (FILT / 2)];
      float wa = roa[a];
      ra0 += __uint_as_float(u << 16) * wa;
      ra1 += __uint_as_float(u & 0xFFFF0000u) * wa;
    }
    rqs[2 * f2] = rq0; rqs[2 * f2 + 1] = rq1;
    ras[2 * f2] = ra0; ras[2 * f2 + 1] = ra1;
  }
  __syncthreads();
  if (tid == 0){
    float dot = 0, n1 = 0, n2 = 0;
    for (int f = 0; f < FILT; f++){ dot += rqs[f] * ras[f]; n1 += rqs[f] * rqs[f]; n2 += ras[f] * ras[f]; }
    float nq = fmaxf(sqrtf(n1), 1e-8f);
    float na = fmaxf(sqrtf(n2), 1e-8f);
    outp[b] = dot / (nq * na);
  }
}

extern "C" void kernel_launch(void* const* d_in, const int* in_sizes, int n_in,
                              void* d_out, int out_size, void* d_ws, size_t ws_size,
                              hipStream_t stream){
  const int*   qtok = (const int*)d_in[0];
  const int*   atok = (const int*)d_in[1];
  const float* emb  = (const float*)d_in[2];
  const float* cw   = (const float*)d_in[3];
  const float* cb   = (const float*)d_in[4];
  const float* W    = (const float*)d_in[5];
  float* outp = (float*)d_out;

  char* ws = (char*)d_ws;
  size_t off = 0;
  auto alloc = [&](size_t bytes) -> char* {
    char* p = ws + off;
    off = (off + bytes + 255) & ~(size_t)255;
    return p;
  };
  u32*   wTf = (u32*)alloc((size_t)KC * NT * 64 * 16);   // 768 KB
  u32*   wF  = (u32*)alloc((size_t)KCF * NT * 64 * 16);  // 333 KB
  u16*   QT  = (u16*)alloc((size_t)BB * LQ * FILT * 2);  // 13.1 MB
  u16*   AT  = (u16*)alloc((size_t)BB * LA * FILT * 2);  // 52.4 MB
  u16*   T   = (u16*)alloc((size_t)BB * LQ * FILT * 2);  // 13.1 MB
  u32*   rme = (u32*)alloc((size_t)BB * LQ * 4);
  float* cm  = (float*)alloc((size_t)BB * LA * 4);

  hipMemsetAsync(rme, 0, (size_t)BB * LQ * 4, stream);   // < encf(any finite)

  k_wt2<<<dim3((KC * NT * 64 + 255) / 256), 256, 0, stream>>>(cw, wTf);
  k_wf<<<dim3((KCF * NT * 64 + 255) / 256), 256, 0, stream>>>(W, wF);
  k_encode_mfma<<<dim3(BB * LQ / MT), 256, 0, stream>>>(qtok, emb, wTf, cb, QT, LQ);
  k_encode_mfma<<<dim3(BB * LA / MT), 256, 0, stream>>>(atok, emb, wTf, cb, AT, LA);
  k_gemmT2<<<dim3(BB * LQ / MT), 256, 0, stream>>>(QT, wF, T);
  k_scores2<<<dim3(LA / 128, BB), 256, 0, stream>>>(T, AT, rme, cm);
  k_final<<<BB, 256, 0, stream>>>(QT, AT, rme, cm, outp);
}

// Round 6
// 275.032 us; speedup vs baseline: 14.0691x; 1.1751x over previous
//
#include <hip/hip_runtime.h>
#include <hip/hip_bf16.h>

// Problem dims (AttentivePoolingNetwork)
#define BB   128
#define LQ   128
#define LA   512
#define EMBD 300
#define FILT 400
#define KW   3

#define NT   25    // n-tiles of 16 (400)
#define KC   30    // k-chunks of 32 for encode (3 emb-blocks padded to 320 each)
#define KCF  13    // k-chunks of 32 over FILT=400 (12 full + 1 zero-padded)
#define MT   32    // rows per block (encode / gemmT)

typedef unsigned short u16;
typedef unsigned int   u32;
typedef __attribute__((ext_vector_type(4))) int    i32x4;
typedef __attribute__((ext_vector_type(4))) float  f32x4;
typedef __attribute__((ext_vector_type(8))) __bf16 bf16x8;

__device__ __forceinline__ float b2f(u16 h){ return __uint_as_float(((u32)h) << 16); }
__device__ __forceinline__ u16 f2b(float f){
  u32 u = __float_as_uint(f);
  u32 r = (u + 0x7FFFu + ((u >> 16) & 1u)) >> 16;   // RNE
  return (u16)r;
}
__device__ __forceinline__ u32 encf(float f){
  u32 u = __float_as_uint(f);
  return (u & 0x80000000u) ? ~u : (u | 0x80000000u);
}
__device__ __forceinline__ float decf(u32 k){
  u32 u = (k & 0x80000000u) ? (k ^ 0x80000000u) : ~k;
  return __uint_as_float(u);
}
__device__ __forceinline__ bf16x8 bzero(){
  i32x4 z; z.x = 0; z.y = 0; z.z = 0; z.w = 0;
  return __builtin_bit_cast(bf16x8, z);
}

// conv_w [F][E][K] fp32 -> wTf in MFMA B-fragment order:
// wTf[kc][nt][lane][j] (bf16), element = B[k'=kc*32+quad*8+j][n=nt*16+(lane&15)]
// k' -> (kk=k'/320, e=k'%320); value = (e<300) ? conv_w[n][e][kk] : 0.
__global__ void k_wt2(const float* __restrict__ cw, u32* __restrict__ wTf){
  int idx = blockIdx.x * 256 + threadIdx.x;
  if (idx >= KC * NT * 64) return;
  int kc  = idx / (NT * 64);
  int rem = idx - kc * (NT * 64);
  int nt  = rem >> 6;
  int lane = rem & 63;
  int n = nt * 16 + (lane & 15);
  int quad = lane >> 4;
  u32 pack[4];
  #pragma unroll
  for (int d = 0; d < 4; d++){
    u16 h[2];
    #pragma unroll
    for (int s = 0; s < 2; s++){
      int kp = kc * 32 + quad * 8 + 2 * d + s;
      int kk = kp / 320, e = kp - kk * 320;
      float v = (e < EMBD) ? cw[(size_t)n * (EMBD * KW) + e * KW + kk] : 0.f;
      h[s] = f2b(v);
    }
    pack[d] = (u32)h[0] | ((u32)h[1] << 16);
  }
  i32x4 out4; out4.x = pack[0]; out4.y = pack[1]; out4.z = pack[2]; out4.w = pack[3];
  *((i32x4*)wTf + idx) = out4;
}

// W [f][g] fp32 -> wF B-fragment order (zero for f>=400).
__global__ void k_wf(const float* __restrict__ W, u32* __restrict__ wF){
  int idx = blockIdx.x * 256 + threadIdx.x;
  if (idx >= KCF * NT * 64) return;
  int kc  = idx / (NT * 64);
  int rem = idx - kc * (NT * 64);
  int nt  = rem >> 6;
  int lane = rem & 63;
  int n = nt * 16 + (lane & 15);
  int quad = lane >> 4;
  u32 pack[4];
  #pragma unroll
  for (int d = 0; d < 4; d++){
    u16 h[2];
    #pragma unroll
    for (int s = 0; s < 2; s++){
      int k = kc * 32 + quad * 8 + 2 * d + s;
      float v = (k < FILT) ? W[(size_t)k * FILT + n] : 0.f;
      h[s] = f2b(v);
    }
    pack[d] = (u32)h[0] | ((u32)h[1] << 16);
  }
  i32x4 out4; out4.x = pack[0]; out4.y = pack[1]; out4.z = pack[2]; out4.w = pack[3];
  *((i32x4*)wF + idx) = out4;
}

// Embed + conv1d(pad=1) as MFMA GEMM, 32 rows x 200-col half per block.
// grid ((B*L)/32, 2): blockIdx.y=0 -> nt 0..12, =1 -> nt 13..24.
// Wave w handles nt = base+w+4j, j<3 (+ j=3 for half 0 wave 0).
// A (gathered emb rows) in LDS; B-frags reg-double-buffered from global wTf.
__global__ __launch_bounds__(256) void k_encode_mfma(const int* __restrict__ toks,
    const float* __restrict__ emb, const u32* __restrict__ wTf,
    const float* __restrict__ bias, u16* __restrict__ out, int L){
  __shared__ u16 At[34 * 328];   // 32+2 halo rows, stride 328

  const int tid  = threadIdx.x;
  const int w    = tid >> 6;
  const int lane = tid & 63;
  const int col  = lane & 15;
  const int quad = lane >> 4;
  const int half = blockIdx.y;
  const int base_nt = half ? 13 : 0;
  const bool has4 = (half == 0) && (w == 0);   // wave-uniform
  const int row0 = blockIdx.x * MT;
  const int b    = row0 / L;
  const int l0   = row0 - b * L;

  for (int i = tid; i < 34 * 328 / 2; i += 256) ((u32*)At)[i] = 0u;
  __syncthreads();
  for (int i = tid; i < 34 * 75; i += 256){
    int r = i / 75, c4 = i - r * 75;
    int pos = l0 - 1 + r;
    if ((unsigned)pos < (unsigned)L){
      int t = toks[b * L + pos];
      float4 v = *((const float4*)(emb + (size_t)t * EMBD) + c4);
      u32 p0 = (u32)f2b(v.x) | ((u32)f2b(v.y) << 16);
      u32 p1 = (u32)f2b(v.z) | ((u32)f2b(v.w) << 16);
      int di = (r * 328 + c4 * 4) >> 1;
      ((u32*)At)[di]     = p0;
      ((u32*)At)[di + 1] = p1;
    }
  }

  f32x4 acc[4][2];
  #pragma unroll
  for (int j = 0; j < 4; j++)
    #pragma unroll
    for (int mf = 0; mf < 2; mf++)
      acc[j][mf] = (f32x4){0.f, 0.f, 0.f, 0.f};

  __syncthreads();

  const i32x4* bbase = (const i32x4*)wTf + (size_t)(base_nt + w) * 64 + lane;
  i32x4 Bb[2][4];
  {
    #pragma unroll
    for (int j = 0; j < 3; j++) Bb[0][j] = bbase[(4 * j) * 64];
    if (has4) Bb[0][3] = bbase[12 * 64];
  }
  #pragma unroll
  for (int kc = 0; kc < KC; kc++){
    const int cur = kc & 1;
    if (kc + 1 < KC){
      const i32x4* s = bbase + (size_t)(kc + 1) * (NT * 64);
      #pragma unroll
      for (int j = 0; j < 3; j++) Bb[cur ^ 1][j] = s[(4 * j) * 64];
      if (has4) Bb[cur ^ 1][3] = s[12 * 64];
    }
    const int kk = kc / 10, e0 = (kc - kk * 10) * 32;
    const int ebase = e0 + quad * 8;
    bf16x8 a0 = __builtin_bit_cast(bf16x8, *(const i32x4*)(At + (col + kk) * 328 + ebase));
    bf16x8 a1 = __builtin_bit_cast(bf16x8, *(const i32x4*)(At + (16 + col + kk) * 328 + ebase));
    #pragma unroll
    for (int j = 0; j < 3; j++){
      bf16x8 bf = __builtin_bit_cast(bf16x8, Bb[cur][j]);
      acc[j][0] = __builtin_amdgcn_mfma_f32_16x16x32_bf16(a0, bf, acc[j][0], 0, 0, 0);
      acc[j][1] = __builtin_amdgcn_mfma_f32_16x16x32_bf16(a1, bf, acc[j][1], 0, 0, 0);
    }
    if (has4){
      bf16x8 bf = __builtin_bit_cast(bf16x8, Bb[cur][3]);
      acc[3][0] = __builtin_amdgcn_mfma_f32_16x16x32_bf16(a0, bf, acc[3][0], 0, 0, 0);
      acc[3][1] = __builtin_amdgcn_mfma_f32_16x16x32_bf16(a1, bf, acc[3][1], 0, 0, 0);
    }
  }

  // epilogue: + bias, bf16 store. C/D: col=lane&15, row=quad*4+reg.
  #pragma unroll
  for (int j = 0; j < 4; j++){
    if (j == 3 && !has4) continue;     // wave-uniform
    int n = (base_nt + w + 4 * j) * 16 + col;
    float bv = bias[n];
    #pragma unroll
    for (int mf = 0; mf < 2; mf++){
      int rbase = row0 + mf * 16 + quad * 4;
      #pragma unroll
      for (int r = 0; r < 4; r++)
        out[(size_t)(rbase + r) * FILT + n] = f2b(acc[j][mf][r] + bv);
    }
  }
}

// T = QT * W, MFMA, no LDS, reg-double-buffered A and B (wF zero-padded tail).
__global__ __launch_bounds__(256) void k_gemmT2(const u16* __restrict__ QT,
    const u32* __restrict__ wF, u16* __restrict__ T){
  const int tid  = threadIdx.x;
  const int w    = tid >> 6;
  const int lane = tid & 63;
  const int col  = lane & 15;
  const int quad = lane >> 4;
  const int row0 = blockIdx.x * MT;

  f32x4 acc[7][2];
  #pragma unroll
  for (int j = 0; j < 7; j++)
    #pragma unroll
    for (int mf = 0; mf < 2; mf++)
      acc[j][mf] = (f32x4){0.f, 0.f, 0.f, 0.f};

  const u16* arow0 = QT + (size_t)(row0 + col) * FILT;
  const u16* arow1 = QT + (size_t)(row0 + 16 + col) * FILT;
  const i32x4* bbase = (const i32x4*)wF + lane;

  i32x4 Ab[2][2];
  i32x4 Bb[2][7];
  {
    int off = quad * 8;
    Ab[0][0] = *(const i32x4*)(arow0 + off);
    Ab[0][1] = *(const i32x4*)(arow1 + off);
    #pragma unroll
    for (int j = 0; j < 6; j++) Bb[0][j] = bbase[(w + 4 * j) * 64];
    if (w == 0) Bb[0][6] = bbase[24 * 64];
  }
  #pragma unroll
  for (int kc = 0; kc < KCF; kc++){
    const int cur = kc & 1;
    if (kc + 1 < KCF){
      int off = (kc + 1) * 32 + quad * 8;
      Ab[cur ^ 1][0] = *(const i32x4*)(arow0 + off);
      Ab[cur ^ 1][1] = *(const i32x4*)(arow1 + off);
      const i32x4* s = bbase + (size_t)(kc + 1) * (NT * 64);
      #pragma unroll
      for (int j = 0; j < 6; j++) Bb[cur ^ 1][j] = s[(w + 4 * j) * 64];
      if (w == 0) Bb[cur ^ 1][6] = s[24 * 64];
    }
    bf16x8 a0 = __builtin_bit_cast(bf16x8, Ab[cur][0]);
    bf16x8 a1 = __builtin_bit_cast(bf16x8, Ab[cur][1]);
    #pragma unroll
    for (int j = 0; j < 6; j++){
      bf16x8 bf = __builtin_bit_cast(bf16x8, Bb[cur][j]);
      acc[j][0] = __builtin_amdgcn_mfma_f32_16x16x32_bf16(a0, bf, acc[j][0], 0, 0, 0);
      acc[j][1] = __builtin_amdgcn_mfma_f32_16x16x32_bf16(a1, bf, acc[j][1], 0, 0, 0);
    }
    if (w == 0){
      bf16x8 bf = __builtin_bit_cast(bf16x8, Bb[cur][6]);
      acc[6][0] = __builtin_amdgcn_mfma_f32_16x16x32_bf16(a0, bf, acc[6][0], 0, 0, 0);
      acc[6][1] = __builtin_amdgcn_mfma_f32_16x16x32_bf16(a1, bf, acc[6][1], 0, 0, 0);
    }
  }

  #pragma unroll
  for (int j = 0; j < 7; j++){
    if (j == 6 && w != 0) continue;
    int nt = (j < 6) ? (w + 4 * j) : 24;
    int n = nt * 16 + col;
    #pragma unroll
    for (int mf = 0; mf < 2; mf++){
      int rbase = row0 + mf * 16 + quad * 4;
      #pragma unroll
      for (int r = 0; r < 4; r++)
        T[(size_t)(rbase + r) * FILT + n] = f2b(acc[j][mf][r]);
    }
  }
}

// Scores S[q][a] = sum_g T[q][g]*AT[a][g] via MFMA; row/col maxes only.
__global__ __launch_bounds__(256) void k_scores2(const u16* __restrict__ T,
    const u16* __restrict__ AT, u32* __restrict__ rowmaxE, float* __restrict__ colmax){
  __shared__ float rpart[128][17];
  __shared__ float cpart[128][17];
  const int tid  = threadIdx.x;
  const int w    = tid >> 6;
  const int lane = tid & 63;
  const int col  = lane & 15;
  const int quad = lane >> 4;
  const int b    = blockIdx.y;
  const int a0   = blockIdx.x * 128;

  f32x4 acc[2][8];
  #pragma unroll
  for (int i = 0; i < 2; i++)
    #pragma unroll
    for (int j = 0; j < 8; j++)
      acc[i][j] = (f32x4){0.f, 0.f, 0.f, 0.f};

  const u16* tr0 = T  + (size_t)(b * LQ + (2 * w) * 16 + col) * FILT;
  const u16* tr1 = T  + (size_t)(b * LQ + (2 * w + 1) * 16 + col) * FILT;
  const u16* ar  = AT + (size_t)(b * LA + a0 + col) * FILT;

  i32x4 Abuf[2][2], Bbuf[2][8];
  {
    int off = quad * 8;
    Abuf[0][0] = *(const i32x4*)(tr0 + off);
    Abuf[0][1] = *(const i32x4*)(tr1 + off);
    #pragma unroll
    for (int j = 0; j < 8; j++)
      Bbuf[0][j] = *(const i32x4*)(ar + (size_t)(j * 16) * FILT + off);
  }
  #pragma unroll
  for (int kc = 0; kc < KCF; kc++){
    const int cur = kc & 1;
    if (kc + 1 < KCF){
      int off = (kc + 1) * 32 + quad * 8;
      Abuf[cur ^ 1][0] = *(const i32x4*)(tr0 + off);
      Abuf[cur ^ 1][1] = *(const i32x4*)(tr1 + off);
      #pragma unroll
      for (int j = 0; j < 8; j++)
        Bbuf[cur ^ 1][j] = *(const i32x4*)(ar + (size_t)(j * 16) * FILT + off);
    }
    const bool live = (kc < 12) || (quad < 2);
    bf16x8 a0 = live ? __builtin_bit_cast(bf16x8, Abuf[cur][0]) : bzero();
    bf16x8 a1 = live ? __builtin_bit_cast(bf16x8, Abuf[cur][1]) : bzero();
    #pragma unroll
    for (int j = 0; j < 8; j++){
      bf16x8 bf = __builtin_bit_cast(bf16x8, Bbuf[cur][j]);
      acc[0][j] = __builtin_amdgcn_mfma_f32_16x16x32_bf16(a0, bf, acc[0][j], 0, 0, 0);
      acc[1][j] = __builtin_amdgcn_mfma_f32_16x16x32_bf16(a1, bf, acc[1][j], 0, 0, 0);
    }
  }

  #pragma unroll
  for (int i = 0; i < 2; i++)
    #pragma unroll
    for (int r = 0; r < 4; r++){
      float m = acc[i][0][r];
      #pragma unroll
      for (int j = 1; j < 8; j++) m = fmaxf(m, acc[i][j][r]);
      rpart[(2 * w + i) * 16 + quad * 4 + r][col] = m;
    }
  #pragma unroll
  for (int j = 0; j < 8; j++){
    float m = acc[0][j][0];
    #pragma unroll
    for (int i = 0; i < 2; i++)
      #pragma unroll
      for (int r = 0; r < 4; r++) m = fmaxf(m, acc[i][j][r]);
    cpart[j * 16 + col][w * 4 + quad] = m;
  }
  __syncthreads();
  if (tid < 128){
    float m = rpart[tid][0];
    #pragma unroll
    for (int g = 1; g < 16; g++) m = fmaxf(m, rpart[tid][g]);
    atomicMax(&rowmaxE[b * LQ + tid], encf(m));
    float m2 = cpart[tid][0];
    #pragma unroll
    for (int g = 1; g < 16; g++) m2 = fmaxf(m2, cpart[tid][g]);
    colmax[b * LA + a0 + tid] = m2;
  }
}

// Softmax weights: roq[b][128], roa[b][512] from rowmaxE/colmax. Parallel reductions.
__global__ __launch_bounds__(256) void k_soft(const u32* __restrict__ rme,
    const float* __restrict__ cm, float* __restrict__ roq, float* __restrict__ roa){
  __shared__ float sq[128];
  __shared__ float sa[512];
  __shared__ float red[4];
  int b = blockIdx.x, tid = threadIdx.x;
  if (tid < 128) sq[tid] = tanhf(decf(rme[b * LQ + tid]));
  sa[tid]       = tanhf(cm[b * LA + tid]);
  sa[tid + 256] = tanhf(cm[b * LA + 256 + tid]);
  __syncthreads();
  if (tid < 64){
    float m = fmaxf(sq[tid], sq[tid + 64]);
    #pragma unroll
    for (int off = 32; off; off >>= 1) m = fmaxf(m, __shfl_down(m, off));
    if (tid == 0) red[0] = m;
  } else if (tid < 128){
    int l = tid - 64;
    float m = sa[l];
    #pragma unroll
    for (int i = 1; i < 8; i++) m = fmaxf(m, sa[l + 64 * i]);
    #pragma unroll
    for (int off = 32; off; off >>= 1) m = fmaxf(m, __shfl_down(m, off));
    if (l == 0) red[1] = m;
  }
  __syncthreads();
  float mq = red[0], ma = red[1];
  if (tid < 128) sq[tid] = __expf(sq[tid] - mq);
  sa[tid]       = __expf(sa[tid] - ma);
  sa[tid + 256] = __expf(sa[tid + 256] - ma);
  __syncthreads();
  if (tid < 64){
    float s = sq[tid] + sq[tid + 64];
    #pragma unroll
    for (int off = 32; off; off >>= 1) s += __shfl_down(s, off);
    if (tid == 0) red[2] = s;
  } else if (tid < 128){
    int l = tid - 64;
    float s = 0.f;
    #pragma unroll
    for (int i = 0; i < 8; i++) s += sa[l + 64 * i];
    #pragma unroll
    for (int off = 32; off; off >>= 1) s += __shfl_down(s, off);
    if (l == 0) red[3] = s;
  }
  __syncthreads();
  float iq = 1.f / red[2], ia = 1.f / red[3];
  if (tid < 128) roq[b * LQ + tid] = sq[tid] * iq;
  roa[b * LA + tid]       = sa[tid] * ia;
  roa[b * LA + 256 + tid] = sa[tid + 256] * ia;
}

// Segment-parallel pooling: grid (4, BB). Segment s: q in [32s,32s+32), a in [128s,128s+128).
// Writes fp32 partials rqp/rap [b][4][FILT].
__global__ __launch_bounds__(256) void k_pool(const u16* __restrict__ QT,
    const u16* __restrict__ AT, const float* __restrict__ roq, const float* __restrict__ roa,
    float* __restrict__ rqp, float* __restrict__ rap){
  __shared__ float wq[32];
  __shared__ float wa[128];
  int s = blockIdx.x, b = blockIdx.y, tid = threadIdx.x;
  if (tid < 32) wq[tid] = roq[b * LQ + s * 32 + tid];
  if (tid >= 128 && tid < 256) wa[tid - 128] = roa[b * LA + s * 128 + (tid - 128)];
  __syncthreads();
  if (tid < FILT / 2){
    const u32* qp = (const u32*)(QT + (size_t)(b * LQ + s * 32) * FILT) + tid;
    const u32* ap = (const u32*)(AT + (size_t)(b * LA + s * 128) * FILT) + tid;
    float rq0 = 0.f, rq1 = 0.f, ra0 = 0.f, ra1 = 0.f;
    for (int q = 0; q < 32; q++){
      u32 u = qp[q * (FILT / 2)];
      float wv = wq[q];
      rq0 += __uint_as_float(u << 16) * wv;
      rq1 += __uint_as_float(u & 0xFFFF0000u) * wv;
    }
    for (int a = 0; a < 128; a++){
      u32 u = ap[a * (FILT / 2)];
      float wv = wa[a];
      ra0 += __uint_as_float(u << 16) * wv;
      ra1 += __uint_as_float(u & 0xFFFF0000u) * wv;
    }
    size_t base = ((size_t)b * 4 + s) * FILT + 2 * tid;
    rqp[base] = rq0; rqp[base + 1] = rq1;
    rap[base] = ra0; rap[base + 1] = ra1;
  }
}

// Reduce 4 partials, cosine similarity. grid (BB), 256 threads.
__global__ __launch_bounds__(256) void k_cos(const float* __restrict__ rqp,
    const float* __restrict__ rap, float* __restrict__ outp){
  __shared__ float rd[4], r1[4], r2[4];
  int b = blockIdx.x, tid = threadIdx.x;
  int lane = tid & 63, w = tid >> 6;
  float d = 0.f, n1 = 0.f, n2 = 0.f;
  for (int f = tid; f < FILT; f += 256){
    size_t base = (size_t)b * 4 * FILT + f;
    float rq = rqp[base] + rqp[base + FILT] + rqp[base + 2 * FILT] + rqp[base + 3 * FILT];
    float ra = rap[base] + rap[base + FILT] + rap[base + 2 * FILT] + rap[base + 3 * FILT];
    d += rq * ra; n1 += rq * rq; n2 += ra * ra;
  }
  #pragma unroll
  for (int off = 32; off; off >>= 1){
    d  += __shfl_down(d, off);
    n1 += __shfl_down(n1, off);
    n2 += __shfl_down(n2, off);
  }
  if (lane == 0){ rd[w] = d; r1[w] = n1; r2[w] = n2; }
  __syncthreads();
  if (tid == 0){
    float D  = rd[0] + rd[1] + rd[2] + rd[3];
    float N1 = r1[0] + r1[1] + r1[2] + r1[3];
    float N2 = r2[0] + r2[1] + r2[2] + r2[3];
    outp[b] = D / (fmaxf(sqrtf(N1), 1e-8f) * fmaxf(sqrtf(N2), 1e-8f));
  }
}

extern "C" void kernel_launch(void* const* d_in, const int* in_sizes, int n_in,
                              void* d_out, int out_size, void* d_ws, size_t ws_size,
                              hipStream_t stream){
  const int*   qtok = (const int*)d_in[0];
  const int*   atok = (const int*)d_in[1];
  const float* emb  = (const float*)d_in[2];
  const float* cw   = (const float*)d_in[3];
  const float* cb   = (const float*)d_in[4];
  const float* W    = (const float*)d_in[5];
  float* outp = (float*)d_out;

  char* ws = (char*)d_ws;
  size_t off = 0;
  auto alloc = [&](size_t bytes) -> char* {
    char* p = ws + off;
    off = (off + bytes + 255) & ~(size_t)255;
    return p;
  };
  u32*   wTf = (u32*)alloc((size_t)KC * NT * 64 * 16);   // 768 KB
  u32*   wF  = (u32*)alloc((size_t)KCF * NT * 64 * 16);  // 333 KB
  u16*   QT  = (u16*)alloc((size_t)BB * LQ * FILT * 2);  // 13.1 MB
  u16*   AT  = (u16*)alloc((size_t)BB * LA * FILT * 2);  // 52.4 MB
  u16*   T   = (u16*)alloc((size_t)BB * LQ * FILT * 2);  // 13.1 MB
  u32*   rme = (u32*)alloc((size_t)BB * LQ * 4);
  float* cm  = (float*)alloc((size_t)BB * LA * 4);
  float* roq = (float*)alloc((size_t)BB * LQ * 4);
  float* roa = (float*)alloc((size_t)BB * LA * 4);
  float* rqp = (float*)alloc((size_t)BB * 4 * FILT * 4); // 819 KB
  float* rap = (float*)alloc((size_t)BB * 4 * FILT * 4); // 819 KB

  hipMemsetAsync(rme, 0, (size_t)BB * LQ * 4, stream);   // < encf(any finite)

  k_wt2<<<dim3((KC * NT * 64 + 255) / 256), 256, 0, stream>>>(cw, wTf);
  k_wf<<<dim3((KCF * NT * 64 + 255) / 256), 256, 0, stream>>>(W, wF);
  k_encode_mfma<<<dim3(BB * LQ / MT, 2), 256, 0, stream>>>(qtok, emb, wTf, cb, QT, LQ);
  k_encode_mfma<<<dim3(BB * LA / MT, 2), 256, 0, stream>>>(atok, emb, wTf, cb, AT, LA);
  k_gemmT2<<<dim3(BB * LQ / MT), 256, 0, stream>>>(QT, wF, T);
  k_scores2<<<dim3(LA / 128, BB), 256, 0, stream>>>(T, AT, rme, cm);
  k_soft<<<dim3(BB), 256, 0, stream>>>(rme, cm, roq, roa);
  k_pool<<<dim3(4, BB), 256, 0, stream>>>(QT, AT, roq, roa, rqp, rap);
  k_cos<<<dim3(BB), 256, 0, stream>>>(rqp, rap, outp);
}